// Round 12
// baseline (220.034 us; speedup 1.0000x reference)
//
#include <hip/hip_runtime.h>

// Problem constants (B,C,H,W = 8,64,128,128; K=3)
#define BATCH 8
#define CIN   64
#define HW    16384      // 128*128
#define CK    576        // CIN*K2

typedef __attribute__((ext_vector_type(8))) short bf16x8;
typedef __attribute__((ext_vector_type(4))) float f32x4;
typedef __attribute__((ext_vector_type(2))) float f32x2;
typedef __attribute__((ext_vector_type(4))) unsigned u32x4;

__device__ inline unsigned short f2bf(float f) {
    unsigned int u = __builtin_bit_cast(unsigned int, f);
    u += 0x7FFFu + ((u >> 16) & 1u);          // round-to-nearest-even
    return (unsigned short)(u >> 16);
}
__device__ inline float bf2f(unsigned short u) {
    return __builtin_bit_cast(float, (unsigned)u << 16);
}
__device__ inline f32x2 upk2(unsigned u) {    // two bf16 in a dword -> f32x2
    f32x2 r;
    r[0] = __builtin_bit_cast(float, u << 16);
    r[1] = __builtin_bit_cast(float, u & 0xFFFF0000u);
    return r;
}
__device__ inline unsigned pk2bf(f32x2 s) {   // manual RNE pack (cold paths)
    return (unsigned)f2bf(s[0]) | ((unsigned)f2bf(s[1]) << 16);
}
__device__ inline unsigned cvtpk(float lo, float hi) {  // HW RNE pack (hot path)
    unsigned r;
    asm("v_cvt_pk_bf16_f32 %0, %1, %2" : "=v"(r) : "v"(lo), "v"(hi));
    return r;
}

// ---------------- ws layout (ushort units) ----------------
// wpack  [18][4][64][8]  deform A-frags      at 0          (36864)
// wcpack [18][2][64][8]  conv A-frags        at 36864      (18432)
// xT     [B][HW][64]     NHWC bf16 input     at 55296      (8388608)

// Fused prep (blocks 0-143) + NCHW->NHWC bf16 LDS transpose (all 2048 blocks).
__global__ __launch_bounds__(256) void prep_transpose(
        const float* __restrict__ x, const float* __restrict__ ow,
        const float* __restrict__ mw, const float* __restrict__ dw,
        unsigned short* __restrict__ wpack, unsigned short* __restrict__ wcpack,
        unsigned short* __restrict__ xT) {
    __shared__ unsigned tile[64 * 36];   // [px][ch-pair], stride 36 dw (144 B, 16-B aligned)
    int t = threadIdx.x, blk = blockIdx.x;
    int b = blk & 7, r2 = blk >> 3;
    int h = r2 >> 1, hf = r2 & 1;
    int px0 = hf << 6;
    // ---- read phase: coalesced float4 loads, pack channel pairs to bf16 dwords
    {
        const float* __restrict__ xb = x + (b * CIN) * HW + (h << 7) + px0;
#pragma unroll
        for (int r = 0; r < 2; r++) {
            int g = r * 256 + t;            // 512 tasks: 32 ch-pairs x 16 col-chunks
            int c2  = g >> 4;               // channel pair 0..31
            int col = (g & 15) << 2;        // pixel col chunk 0..60
            f32x4 lo = *(const f32x4*)(xb + (2 * c2) * HW + col);
            f32x4 hi = *(const f32x4*)(xb + (2 * c2 + 1) * HW + col);
#pragma unroll
            for (int i = 0; i < 4; i++) {
                f32x2 s; s[0] = lo[i]; s[1] = hi[i];
                tile[(col + i) * 36 + c2] = pk2bf(s);
            }
        }
    }
    __syncthreads();
    // ---- write phase: wave writes 2 KB contiguous (16 px x 128 B records)
    {
        int p = t >> 2, q = t & 3;          // pixel 0..63, 32-B chunk 0..3
        const unsigned* s = &tile[p * 36 + (q << 3)];
        u32x4 v0 = *(const u32x4*)(s);
        u32x4 v1 = *(const u32x4*)(s + 4);
        int pix = (h << 7) + px0 + p;
        unsigned short* dst = xT + ((b * HW + pix) << 6) + (q << 4);
        *(u32x4*)dst = v0;
        *(u32x4*)(dst + 8) = v1;
    }
    // ---- prep part (first 144 blocks)
    int g = blk * 256 + t;
    if (g < 18 * 4 * 64 * 8) {           // deform weights: dw[o][c][tap]
        int j = g & 7, lane = (g >> 3) & 63, ot = (g >> 9) & 3, gks = g >> 11;
        int o = ot * 16 + (lane & 15);
        int s = gks * 32 + ((lane >> 4) & 3) * 8 + j;
        int c = s & 63, tap = s >> 6;
        wpack[g] = f2bf(dw[o * CK + c * 9 + tap]);
    }
    if (g < 18 * 2 * 64 * 8) {           // conv weights: rows 0-17 ow, 18-26 mw
        int j = g & 7, lane = (g >> 3) & 63, ot = (g >> 9) & 1, gks = g >> 10;
        int o = ot * 16 + (lane & 15);
        int s = gks * 32 + ((lane >> 4) & 3) * 8 + j;
        int c = s & 63, tap = s >> 6;
        float v = 0.f;
        if (o < 18)      v = ow[(o * 64 + c) * 9 + tap];
        else if (o < 27) v = mw[((o - 18) * 64 + c) * 9 + tap];
        wcpack[g] = f2bf(v);
    }
}

// Fused offset/mask conv + deformable conv. Block = 64 px (half row).
// R21 = R20 (combine-before-stash, 5 blocks/CU) + three latency cuts:
//  - ALL 9 taps' corner rows hoisted to registers (rA/rB, 36 VGPR, static
//    idx under full unroll) — removes per-tap rtab lgkm dependency at the
//    head of the gather chain.
//  - wave-staggered ot order: wave pt computes physical ot=(oti+pt)&3 so
//    concurrent waves pull different wpack af lines (no L1 convoy). acc
//    index stays static (rule #20).
//  - s_setprio(1) around the MFMA cluster (barrier-free phase -> scheduler
//    has arbitration choices; T5 attn-regime).
__global__ __launch_bounds__(256, 5) void fused_kernel(
        const unsigned short* __restrict__ xT, const unsigned short* __restrict__ wcpack,
        const unsigned short* __restrict__ wpack,
        const float* __restrict__ ob, const float* __restrict__ mb,
        const float* __restrict__ dbv, float* __restrict__ out) {
    __shared__ __align__(16) unsigned short buf[14256];   // 28,512 B total
    // lifetime-disjoint overlays (all within buf):
    unsigned short* omrow = buf;                 // [27][64] ush   [0,1728)    live A-epi..B
    float*          wtab  = (float*)&buf[1728];  // [576][4] f32   [1728,6336) live B..C
    unsigned short* rtab  = &buf[6336];          // [576][4] ush   [6336,8640) live B..C
    unsigned short* stash = &buf[8640];          // 4 waves x 1024 [8640,12736) live C

    int t = threadIdx.x;
    int lane = t & 63, pt = t >> 6, quad = lane >> 4, n = lane & 15;
    int blk = blockIdx.x;
    int b = blk & 7, r2 = blk >> 3;
    int h = r2 >> 1, hf = r2 & 1;
    int px0 = hf << 6;
    int pxl = (pt << 4) + n;          // this lane's pixel within the 64-px block
    int gx  = px0 + pxl;

    const unsigned short* __restrict__ xtb = xT + ((b * HW) << 6);
    const short zs = 0;
    const bf16x8 zv = {zs, zs, zs, zs, zs, zs, zs, zs};

    // ========== Stage 1: halo tile (rows h-1..h+1, cols px0-1..px0+64) ==========
    for (int i = t; i < 1584; i += 256) {       // 198 rows x 8 slices
        int s  = i & 7;
        int rc = i >> 3;                        // 0..197
        int r  = rc / 66, col = rc - r * 66;
        int gy  = h - 1 + r;
        int gxc = px0 - 1 + col;
        bf16x8 v = zv;
        if ((unsigned)gy < 128u && (unsigned)gxc < 128u)
            v = *(const bf16x8*)(xtb + (((gy << 7) + gxc) << 6) + (s << 3));
        *(bf16x8*)&buf[rc * 72 + (s << 3)] = v;
    }
    __syncthreads();

    // ========== Phase A: offset/mask conv from LDS tile ==========
    f32x4 acc0 = {0.f, 0.f, 0.f, 0.f}, acc1 = {0.f, 0.f, 0.f, 0.f};
#pragma unroll
    for (int tap = 0; tap < 9; tap++) {
        int r = tap / 3, cm = tap % 3;
        const unsigned short* srcA = &buf[(r * 66 + pxl + cm) * 72];
#pragma unroll
        for (int kk = 0; kk < 2; kk++) {
            bf16x8 bfrag = *(const bf16x8*)(srcA + (kk << 5) + (quad << 3));
            int gks = tap * 2 + kk;
            bf16x8 a0 = *(const bf16x8*)(wcpack + ((gks * 2 + 0) * 64 + lane) * 8);
            bf16x8 a1 = *(const bf16x8*)(wcpack + ((gks * 2 + 1) * 64 + lane) * 8);
            acc0 = __builtin_amdgcn_mfma_f32_16x16x32_bf16(a0, bfrag, acc0, 0, 0, 0);
            acc1 = __builtin_amdgcn_mfma_f32_16x16x32_bf16(a1, bfrag, acc1, 0, 0, 0);
        }
    }
    __syncthreads();   // tile reads complete before omrow overwrites tile rows

    // epilogue -> omrow (overlays dead tile rows), o-major [27][64]
#pragma unroll
    for (int r = 0; r < 4; r++) {
        int o = quad * 4 + r;
        omrow[o * 64 + pxl] = f2bf(acc0[r] + ob[o]);
    }
#pragma unroll
    for (int r = 0; r < 4; r++) {
        int o = 16 + quad * 4 + r;
        if (o < 27) {
            float v = acc1[r];
            if (o < 18) v += ob[o];
            else { v += mb[o - 18]; v = 1.f / (1.f + __expf(-v)); }
            omrow[o * 64 + pxl] = f2bf(v);
        }
    }
    __syncthreads();

    // ========== Phase B: full bilinear params -> wtab (f32x4) + rtab (4 rows) ==========
    for (int g = t; g < 576; g += 256) {
        int px = g / 9, k = g - px * 9;
        float dy = bf2f(omrow[(2 * k) * 64 + px]);
        float dx = bf2f(omrow[(2 * k + 1) * 64 + px]);
        float mk = bf2f(omrow[(18 + k) * 64 + px]);
        float py  = (float)h + (float)(k / 3 - 1) + dy;
        float pxx = (float)(px0 + px) + (float)(k % 3 - 1) + dx;
        float fy = floorf(py), fx = floorf(pxx);
        float ly = py - fy, lx = pxx - fx;
        int y0 = (int)fy, x0 = (int)fx;
        bool y0v = (unsigned)y0 < 128u, y1v = (unsigned)(y0 + 1) < 128u;
        bool x0v = (unsigned)x0 < 128u, x1v = (unsigned)(x0 + 1) < 128u;
        f32x4 wv;
        wv[0] = (y0v && x0v) ? (1.f - ly) * (1.f - lx) * mk : 0.f;
        wv[1] = (y0v && x1v) ? (1.f - ly) * lx * mk : 0.f;
        wv[2] = (y1v && x0v) ? ly * (1.f - lx) * mk : 0.f;
        wv[3] = (y1v && x1v) ? ly * lx * mk : 0.f;
        *(f32x4*)&wtab[g * 4] = wv;
        int y0c = min(max(y0, 0), 127), x0c = min(max(x0, 0), 127);
        unsigned dxb = (x0 >= 0 && x0 < 127) ? 1u : 0u;
        unsigned dyb = (y0 >= 0 && y0 < 127) ? 128u : 0u;
        unsigned r00 = (unsigned)((y0c << 7) + x0c);
        uint2 u; u.x = r00 | ((r00 + dxb) << 16); u.y = (r00 + dyb) | ((r00 + dyb + dxb) << 16);
        *(uint2*)&rtab[g * 4] = u;
    }
    __syncthreads();

    // ========== Phase C: combine-before-stash, rows hoisted, 1-tap prefetch ==========
    f32x4 acc[4];
#pragma unroll
    for (int ot = 0; ot < 4; ot++) acc[ot] = (f32x4){0.f, 0.f, 0.f, 0.f};

    // gather tasks: lane handles wave-local pixels pxg and pxg+8, slice s7
    int s7    = lane & 7;
    int soffu = s7 << 3;
    int pxg   = lane >> 3;                   // 0..7
    unsigned short* stw = stash + (pt << 10);      // wave's 1024-ush stash
    int swk   = (s7 ^ (pxg & 7)) << 3;             // swizzled slot (same for px, px+8)
    int wadr0 = (pxg << 6) + swk;
    int wadr1 = ((pxg + 8) << 6) + swk;
    int rad0  = (n << 6) + (((quad) ^ (n & 7)) << 3);        // kk=0 slot
    int rad1  = (n << 6) + (((4 + quad) ^ (n & 7)) << 3);    // kk=1 slot
    int ta    = ((pt << 4) + pxg) * 9;       // block-local pixel index (R20 fix)
    int tb    = ((pt << 4) + pxg + 8) * 9;

    // R21: hoist ALL taps' corner rows to registers (static idx under unroll)
    uint2 rA[9], rB[9];
#pragma unroll
    for (int k = 0; k < 9; k++) {
        rA[k] = *(const uint2*)&rtab[(ta + k) * 4];
        rB[k] = *(const uint2*)&rtab[(tb + k) * 4];
    }

    bf16x8 pf[8];                            // [task 0..1][corner 0..3]
    {
        pf[0] = *(const bf16x8*)(xtb + ((rA[0].x & 0xFFFF) << 6) + soffu);
        pf[1] = *(const bf16x8*)(xtb + ((rA[0].x >> 16) << 6) + soffu);
        pf[2] = *(const bf16x8*)(xtb + ((rA[0].y & 0xFFFF) << 6) + soffu);
        pf[3] = *(const bf16x8*)(xtb + ((rA[0].y >> 16) << 6) + soffu);
        pf[4] = *(const bf16x8*)(xtb + ((rB[0].x & 0xFFFF) << 6) + soffu);
        pf[5] = *(const bf16x8*)(xtb + ((rB[0].x >> 16) << 6) + soffu);
        pf[6] = *(const bf16x8*)(xtb + ((rB[0].y & 0xFFFF) << 6) + soffu);
        pf[7] = *(const bf16x8*)(xtb + ((rB[0].y >> 16) << 6) + soffu);
    }

#pragma unroll
    for (int tap = 0; tap < 9; tap++) {
        // issue next tap's corner loads (rows already in registers)
        bf16x8 nf[8];
        if (tap < 8) {
            uint2 ra = rA[(tap + 1 < 9) ? tap + 1 : 8];
            uint2 rb = rB[(tap + 1 < 9) ? tap + 1 : 8];
            nf[0] = *(const bf16x8*)(xtb + ((ra.x & 0xFFFF) << 6) + soffu);
            nf[1] = *(const bf16x8*)(xtb + ((ra.x >> 16) << 6) + soffu);
            nf[2] = *(const bf16x8*)(xtb + ((ra.y & 0xFFFF) << 6) + soffu);
            nf[3] = *(const bf16x8*)(xtb + ((ra.y >> 16) << 6) + soffu);
            nf[4] = *(const bf16x8*)(xtb + ((rb.x & 0xFFFF) << 6) + soffu);
            nf[5] = *(const bf16x8*)(xtb + ((rb.x >> 16) << 6) + soffu);
            nf[6] = *(const bf16x8*)(xtb + ((rb.y & 0xFFFF) << 6) + soffu);
            nf[7] = *(const bf16x8*)(xtb + ((rb.y >> 16) << 6) + soffu);
        }
        // combine both tasks in-register (same math order as R15: w0,w1,w2,w3)
#pragma unroll
        for (int i = 0; i < 2; i++) {
            f32x4 wv = *(const f32x4*)&wtab[((i ? tb : ta) + tap) * 4];
            f32x2 W0 = {wv[0], wv[0]}, W1 = {wv[1], wv[1]};
            f32x2 W2 = {wv[2], wv[2]}, W3 = {wv[3], wv[3]};
            const unsigned* u0 = (const unsigned*)&pf[i * 4 + 0];
            const unsigned* u1 = (const unsigned*)&pf[i * 4 + 1];
            const unsigned* u2 = (const unsigned*)&pf[i * 4 + 2];
            const unsigned* u3 = (const unsigned*)&pf[i * 4 + 3];
            bf16x8 bc;
            unsigned* bu = (unsigned*)&bc;
#pragma unroll
            for (int jj = 0; jj < 4; jj++) {
                f32x2 s2 = upk2(u0[jj]) * W0 + upk2(u1[jj]) * W1
                         + upk2(u2[jj]) * W2 + upk2(u3[jj]) * W3;
                bu[jj] = cvtpk(s2[0], s2[1]);
            }
            *(bf16x8*)&stw[i ? wadr1 : wadr0] = bc;
        }
        // read own pixel's finished bfrags + MFMA (same-wave DS order: R15-proven)
#pragma unroll
        for (int kk = 0; kk < 2; kk++) {
            bf16x8 bfrag = *(const bf16x8*)&stw[kk ? rad1 : rad0];
            int gks = tap * 2 + kk;
            __builtin_amdgcn_s_setprio(1);
#pragma unroll
            for (int oti = 0; oti < 4; oti++) {
                int otp = (oti + pt) & 3;    // wave-staggered physical ot (af addr only)
                bf16x8 af = *(const bf16x8*)(wpack + ((gks * 4 + otp) * 64 + lane) * 8);
                acc[oti] = __builtin_amdgcn_mfma_f32_16x16x32_bf16(af, bfrag, acc[oti], 0, 0, 0);
            }
            __builtin_amdgcn_s_setprio(0);
        }
        if (tap < 8) {
#pragma unroll
            for (int i = 0; i < 8; i++) pf[i] = nf[i];
        }
    }

    // ---- epilogue: D col(lane&15)=px, row = otp*16 + quad*4 + r = o
    int opix = (h << 7) + px0 + (pt << 4) + n;
#pragma unroll
    for (int oti = 0; oti < 4; oti++) {
        int otp = (oti + pt) & 3;
#pragma unroll
        for (int r = 0; r < 4; r++) {
            int o = otp * 16 + quad * 4 + r;
            out[(b * 64 + o) * HW + opix] = acc[oti][r] + dbv[o];
        }
    }
}

extern "C" void kernel_launch(void* const* d_in, const int* in_sizes, int n_in,
                              void* d_out, int out_size, void* d_ws, size_t ws_size,
                              hipStream_t stream) {
    const float* x   = (const float*)d_in[0];
    const float* ow  = (const float*)d_in[1];
    const float* ob  = (const float*)d_in[2];
    const float* mw  = (const float*)d_in[3];
    const float* mb  = (const float*)d_in[4];
    const float* dw  = (const float*)d_in[5];
    const float* dbv = (const float*)d_in[6];
    float* out = (float*)d_out;

    unsigned short* wpack  = (unsigned short*)d_ws;          // 36864
    unsigned short* wcpack = wpack + 36864;                  // 18432
    unsigned short* xT     = wpack + 55296;                  // 8388608

    prep_transpose<<<2048, 256, 0, stream>>>(x, ow, mw, dw, wpack, wcpack, xT);
    fused_kernel<<<2048, 256, 0, stream>>>(xT, wcpack, wpack, ob, mb, dbv, out);
}

// Round 13
// 161.604 us; speedup vs baseline: 1.3616x; 1.3616x over previous
//
#include <hip/hip_runtime.h>

// Problem constants (B,C,H,W = 8,64,128,128; K=3)
#define BATCH 8
#define CIN   64
#define HW    16384      // 128*128
#define CK    576        // CIN*K2

typedef __attribute__((ext_vector_type(8))) short bf16x8;
typedef __attribute__((ext_vector_type(4))) float f32x4;
typedef __attribute__((ext_vector_type(2))) float f32x2;
typedef __attribute__((ext_vector_type(4))) unsigned u32x4;

__device__ inline unsigned short f2bf(float f) {
    unsigned int u = __builtin_bit_cast(unsigned int, f);
    u += 0x7FFFu + ((u >> 16) & 1u);          // round-to-nearest-even
    return (unsigned short)(u >> 16);
}
__device__ inline float bf2f(unsigned short u) {
    return __builtin_bit_cast(float, (unsigned)u << 16);
}
__device__ inline f32x2 upk2(unsigned u) {    // two bf16 in a dword -> f32x2
    f32x2 r;
    r[0] = __builtin_bit_cast(float, u << 16);
    r[1] = __builtin_bit_cast(float, u & 0xFFFF0000u);
    return r;
}
__device__ inline unsigned pk2bf(f32x2 s) {   // manual RNE pack (cold paths)
    return (unsigned)f2bf(s[0]) | ((unsigned)f2bf(s[1]) << 16);
}
__device__ inline unsigned cvtpk(float lo, float hi) {  // HW RNE pack (hot path)
    unsigned r;
    asm("v_cvt_pk_bf16_f32 %0, %1, %2" : "=v"(r) : "v"(lo), "v"(hi));
    return r;
}

// ---------------- ws layout (ushort units) ----------------
// wpack  [18][4][64][8]  deform A-frags      at 0          (36864)
// wcpack [18][2][64][8]  conv A-frags        at 36864      (18432)
// xT     [B][HW][64]     NHWC bf16 input     at 55296      (8388608)

// Fused prep (blocks 0-143) + NCHW->NHWC bf16 LDS transpose (all 2048 blocks).
__global__ __launch_bounds__(256) void prep_transpose(
        const float* __restrict__ x, const float* __restrict__ ow,
        const float* __restrict__ mw, const float* __restrict__ dw,
        unsigned short* __restrict__ wpack, unsigned short* __restrict__ wcpack,
        unsigned short* __restrict__ xT) {
    __shared__ unsigned tile[64 * 36];   // [px][ch-pair], stride 36 dw (144 B, 16-B aligned)
    int t = threadIdx.x, blk = blockIdx.x;
    int b = blk & 7, r2 = blk >> 3;
    int h = r2 >> 1, hf = r2 & 1;
    int px0 = hf << 6;
    // ---- read phase: coalesced float4 loads, pack channel pairs to bf16 dwords
    {
        const float* __restrict__ xb = x + (b * CIN) * HW + (h << 7) + px0;
#pragma unroll
        for (int r = 0; r < 2; r++) {
            int g = r * 256 + t;            // 512 tasks: 32 ch-pairs x 16 col-chunks
            int c2  = g >> 4;               // channel pair 0..31
            int col = (g & 15) << 2;        // pixel col chunk 0..60
            f32x4 lo = *(const f32x4*)(xb + (2 * c2) * HW + col);
            f32x4 hi = *(const f32x4*)(xb + (2 * c2 + 1) * HW + col);
#pragma unroll
            for (int i = 0; i < 4; i++) {
                f32x2 s; s[0] = lo[i]; s[1] = hi[i];
                tile[(col + i) * 36 + c2] = pk2bf(s);
            }
        }
    }
    __syncthreads();
    // ---- write phase: wave writes 2 KB contiguous (16 px x 128 B records)
    {
        int p = t >> 2, q = t & 3;          // pixel 0..63, 32-B chunk 0..3
        const unsigned* s = &tile[p * 36 + (q << 3)];
        u32x4 v0 = *(const u32x4*)(s);
        u32x4 v1 = *(const u32x4*)(s + 4);
        int pix = (h << 7) + px0 + p;
        unsigned short* dst = xT + ((b * HW + pix) << 6) + (q << 4);
        *(u32x4*)dst = v0;
        *(u32x4*)(dst + 8) = v1;
    }
    // ---- prep part (first 144 blocks)
    int g = blk * 256 + t;
    if (g < 18 * 4 * 64 * 8) {           // deform weights: dw[o][c][tap]
        int j = g & 7, lane = (g >> 3) & 63, ot = (g >> 9) & 3, gks = g >> 11;
        int o = ot * 16 + (lane & 15);
        int s = gks * 32 + ((lane >> 4) & 3) * 8 + j;
        int c = s & 63, tap = s >> 6;
        wpack[g] = f2bf(dw[o * CK + c * 9 + tap]);
    }
    if (g < 18 * 2 * 64 * 8) {           // conv weights: rows 0-17 ow, 18-26 mw
        int j = g & 7, lane = (g >> 3) & 63, ot = (g >> 9) & 1, gks = g >> 10;
        int o = ot * 16 + (lane & 15);
        int s = gks * 32 + ((lane >> 4) & 3) * 8 + j;
        int c = s & 63, tap = s >> 6;
        float v = 0.f;
        if (o < 18)      v = ow[(o * 64 + c) * 9 + tap];
        else if (o < 27) v = mw[((o - 18) * 64 + c) * 9 + tap];
        wcpack[g] = f2bf(v);
    }
}

// Fused offset/mask conv + deformable conv. Block = 64 px (half row).
// R22 = R20 EXACTLY (combine-before-stash; R21's 3-change bundle spilled —
// all reverted) + tile pad removed: halo tile stride 72 -> 64 ush with XOR
// swizzle (slot ^= row&7, 16-B granular, SAME involution on Stage-1 write
// and Phase-A read). Bank analysis: swizzled unpadded layout keeps both
// patterns at the 8-round b128 floor. Buffer 28,512 -> 25,472 B ->
// 6 blocks/CU (24 waves, +20%). VGPR cap 85 (R20 used 48).
__global__ __launch_bounds__(256, 6) void fused_kernel(
        const unsigned short* __restrict__ xT, const unsigned short* __restrict__ wcpack,
        const unsigned short* __restrict__ wpack,
        const float* __restrict__ ob, const float* __restrict__ mb,
        const float* __restrict__ dbv, float* __restrict__ out) {
    __shared__ __align__(16) unsigned short buf[12736];   // 25,472 B total
    // tile: 198 rows x 64 ush, XOR-swizzled          [0,12672)  live S1..A
    // lifetime-disjoint overlays:
    unsigned short* omrow = buf;                 // [27][64] ush   [0,1728)    live A-epi..B
    float*          wtab  = (float*)&buf[1728];  // [576][4] f32   [1728,6336) live B..C
    unsigned short* rtab  = &buf[6336];          // [576][4] ush   [6336,8640) live B..C
    unsigned short* stash = &buf[8640];          // 4 waves x 1024 [8640,12736) live C

    int t = threadIdx.x;
    int lane = t & 63, pt = t >> 6, quad = lane >> 4, n = lane & 15;
    int blk = blockIdx.x;
    int b = blk & 7, r2 = blk >> 3;
    int h = r2 >> 1, hf = r2 & 1;
    int px0 = hf << 6;
    int pxl = (pt << 4) + n;          // this lane's pixel within the 64-px block
    int gx  = px0 + pxl;

    const unsigned short* __restrict__ xtb = xT + ((b * HW) << 6);
    const short zs = 0;
    const bf16x8 zv = {zs, zs, zs, zs, zs, zs, zs, zs};

    // ========== Stage 1: halo tile (rows h-1..h+1, cols px0-1..px0+64) ==========
    for (int i = t; i < 1584; i += 256) {       // 198 rows x 8 slices
        int s  = i & 7;
        int rc = i >> 3;                        // 0..197
        int r  = rc / 66, col = rc - r * 66;
        int gy  = h - 1 + r;
        int gxc = px0 - 1 + col;
        bf16x8 v = zv;
        if ((unsigned)gy < 128u && (unsigned)gxc < 128u)
            v = *(const bf16x8*)(xtb + (((gy << 7) + gxc) << 6) + (s << 3));
        *(bf16x8*)&buf[(rc << 6) + (((s ^ (rc & 7)) << 3))] = v;   // swizzled slot
    }
    __syncthreads();

    // ========== Phase A: offset/mask conv from LDS tile (swizzled reads) ==========
    f32x4 acc0 = {0.f, 0.f, 0.f, 0.f}, acc1 = {0.f, 0.f, 0.f, 0.f};
#pragma unroll
    for (int tap = 0; tap < 9; tap++) {
        int r = tap / 3, cm = tap % 3;
        int row = r * 66 + pxl + cm;
        const unsigned short* srcA = &buf[row << 6];
        int rk = (row & 7);
#pragma unroll
        for (int kk = 0; kk < 2; kk++) {
            int slot = (kk << 2) + quad;         // 8-ush slot index 0..7
            bf16x8 bfrag = *(const bf16x8*)(srcA + ((slot ^ rk) << 3));
            int gks = tap * 2 + kk;
            bf16x8 a0 = *(const bf16x8*)(wcpack + ((gks * 2 + 0) * 64 + lane) * 8);
            bf16x8 a1 = *(const bf16x8*)(wcpack + ((gks * 2 + 1) * 64 + lane) * 8);
            acc0 = __builtin_amdgcn_mfma_f32_16x16x32_bf16(a0, bfrag, acc0, 0, 0, 0);
            acc1 = __builtin_amdgcn_mfma_f32_16x16x32_bf16(a1, bfrag, acc1, 0, 0, 0);
        }
    }
    __syncthreads();   // tile reads complete before omrow overwrites tile rows

    // epilogue -> omrow (overlays dead tile rows), o-major [27][64]
#pragma unroll
    for (int r = 0; r < 4; r++) {
        int o = quad * 4 + r;
        omrow[o * 64 + pxl] = f2bf(acc0[r] + ob[o]);
    }
#pragma unroll
    for (int r = 0; r < 4; r++) {
        int o = 16 + quad * 4 + r;
        if (o < 27) {
            float v = acc1[r];
            if (o < 18) v += ob[o];
            else { v += mb[o - 18]; v = 1.f / (1.f + __expf(-v)); }
            omrow[o * 64 + pxl] = f2bf(v);
        }
    }
    __syncthreads();

    // ========== Phase B: full bilinear params -> wtab (f32x4) + rtab (4 rows) ==========
    for (int g = t; g < 576; g += 256) {
        int px = g / 9, k = g - px * 9;
        float dy = bf2f(omrow[(2 * k) * 64 + px]);
        float dx = bf2f(omrow[(2 * k + 1) * 64 + px]);
        float mk = bf2f(omrow[(18 + k) * 64 + px]);
        float py  = (float)h + (float)(k / 3 - 1) + dy;
        float pxx = (float)(px0 + px) + (float)(k % 3 - 1) + dx;
        float fy = floorf(py), fx = floorf(pxx);
        float ly = py - fy, lx = pxx - fx;
        int y0 = (int)fy, x0 = (int)fx;
        bool y0v = (unsigned)y0 < 128u, y1v = (unsigned)(y0 + 1) < 128u;
        bool x0v = (unsigned)x0 < 128u, x1v = (unsigned)(x0 + 1) < 128u;
        f32x4 wv;
        wv[0] = (y0v && x0v) ? (1.f - ly) * (1.f - lx) * mk : 0.f;
        wv[1] = (y0v && x1v) ? (1.f - ly) * lx * mk : 0.f;
        wv[2] = (y1v && x0v) ? ly * (1.f - lx) * mk : 0.f;
        wv[3] = (y1v && x1v) ? ly * lx * mk : 0.f;
        *(f32x4*)&wtab[g * 4] = wv;
        int y0c = min(max(y0, 0), 127), x0c = min(max(x0, 0), 127);
        unsigned dxb = (x0 >= 0 && x0 < 127) ? 1u : 0u;
        unsigned dyb = (y0 >= 0 && y0 < 127) ? 128u : 0u;
        unsigned r00 = (unsigned)((y0c << 7) + x0c);
        uint2 u; u.x = r00 | ((r00 + dxb) << 16); u.y = (r00 + dyb) | ((r00 + dyb + dxb) << 16);
        *(uint2*)&rtab[g * 4] = u;
    }
    __syncthreads();

    // ========== Phase C: combine-before-stash, 1-tap prefetch ==========
    f32x4 acc[4];
#pragma unroll
    for (int ot = 0; ot < 4; ot++) acc[ot] = (f32x4){0.f, 0.f, 0.f, 0.f};

    // gather tasks: lane handles wave-local pixels pxg and pxg+8, slice s7
    int s7    = lane & 7;
    int soffu = s7 << 3;
    int pxg   = lane >> 3;                   // 0..7
    unsigned short* stw = stash + (pt << 10);      // wave's 1024-ush stash
    int swk   = (s7 ^ (pxg & 7)) << 3;             // swizzled slot (same for px, px+8)
    int wadr0 = (pxg << 6) + swk;
    int wadr1 = ((pxg + 8) << 6) + swk;
    int rad0  = (n << 6) + (((quad) ^ (n & 7)) << 3);        // kk=0 slot
    int rad1  = (n << 6) + (((4 + quad) ^ (n & 7)) << 3);    // kk=1 slot
    int ta    = ((pt << 4) + pxg) * 9;       // block-local pixel index
    int tb    = ((pt << 4) + pxg + 8) * 9;

    bf16x8 pf[8];                            // [task 0..1][corner 0..3]
    {
        uint2 ra = *(const uint2*)&rtab[ta * 4];
        uint2 rb = *(const uint2*)&rtab[tb * 4];
        pf[0] = *(const bf16x8*)(xtb + ((ra.x & 0xFFFF) << 6) + soffu);
        pf[1] = *(const bf16x8*)(xtb + ((ra.x >> 16) << 6) + soffu);
        pf[2] = *(const bf16x8*)(xtb + ((ra.y & 0xFFFF) << 6) + soffu);
        pf[3] = *(const bf16x8*)(xtb + ((ra.y >> 16) << 6) + soffu);
        pf[4] = *(const bf16x8*)(xtb + ((rb.x & 0xFFFF) << 6) + soffu);
        pf[5] = *(const bf16x8*)(xtb + ((rb.x >> 16) << 6) + soffu);
        pf[6] = *(const bf16x8*)(xtb + ((rb.y & 0xFFFF) << 6) + soffu);
        pf[7] = *(const bf16x8*)(xtb + ((rb.y >> 16) << 6) + soffu);
    }

#pragma unroll
    for (int tap = 0; tap < 9; tap++) {
        // issue next tap's corner loads (latency hidden behind combine+MFMA)
        bf16x8 nf[8];
        if (tap < 8) {
            uint2 ra = *(const uint2*)&rtab[(ta + tap + 1) * 4];
            uint2 rb = *(const uint2*)&rtab[(tb + tap + 1) * 4];
            nf[0] = *(const bf16x8*)(xtb + ((ra.x & 0xFFFF) << 6) + soffu);
            nf[1] = *(const bf16x8*)(xtb + ((ra.x >> 16) << 6) + soffu);
            nf[2] = *(const bf16x8*)(xtb + ((ra.y & 0xFFFF) << 6) + soffu);
            nf[3] = *(const bf16x8*)(xtb + ((ra.y >> 16) << 6) + soffu);
            nf[4] = *(const bf16x8*)(xtb + ((rb.x & 0xFFFF) << 6) + soffu);
            nf[5] = *(const bf16x8*)(xtb + ((rb.x >> 16) << 6) + soffu);
            nf[6] = *(const bf16x8*)(xtb + ((rb.y & 0xFFFF) << 6) + soffu);
            nf[7] = *(const bf16x8*)(xtb + ((rb.y >> 16) << 6) + soffu);
        }
        // combine both tasks in-register (same math order: w0,w1,w2,w3)
#pragma unroll
        for (int i = 0; i < 2; i++) {
            f32x4 wv = *(const f32x4*)&wtab[((i ? tb : ta) + tap) * 4];
            f32x2 W0 = {wv[0], wv[0]}, W1 = {wv[1], wv[1]};
            f32x2 W2 = {wv[2], wv[2]}, W3 = {wv[3], wv[3]};
            const unsigned* u0 = (const unsigned*)&pf[i * 4 + 0];
            const unsigned* u1 = (const unsigned*)&pf[i * 4 + 1];
            const unsigned* u2 = (const unsigned*)&pf[i * 4 + 2];
            const unsigned* u3 = (const unsigned*)&pf[i * 4 + 3];
            bf16x8 bc;
            unsigned* bu = (unsigned*)&bc;
#pragma unroll
            for (int jj = 0; jj < 4; jj++) {
                f32x2 s2 = upk2(u0[jj]) * W0 + upk2(u1[jj]) * W1
                         + upk2(u2[jj]) * W2 + upk2(u3[jj]) * W3;
                bu[jj] = cvtpk(s2[0], s2[1]);
            }
            *(bf16x8*)&stw[i ? wadr1 : wadr0] = bc;
        }
        // read own pixel's finished bfrags + MFMA (same-wave DS order)
#pragma unroll
        for (int kk = 0; kk < 2; kk++) {
            bf16x8 bfrag = *(const bf16x8*)&stw[kk ? rad1 : rad0];
            int gks = tap * 2 + kk;
#pragma unroll
            for (int ot = 0; ot < 4; ot++) {
                bf16x8 af = *(const bf16x8*)(wpack + ((gks * 4 + ot) * 64 + lane) * 8);
                acc[ot] = __builtin_amdgcn_mfma_f32_16x16x32_bf16(af, bfrag, acc[ot], 0, 0, 0);
            }
        }
        if (tap < 8) {
#pragma unroll
            for (int i = 0; i < 8; i++) pf[i] = nf[i];
        }
    }

    // ---- epilogue: D col(lane&15)=px, row = ot*16 + quad*4 + r = o
    int opix = (h << 7) + px0 + (pt << 4) + n;
#pragma unroll
    for (int ot = 0; ot < 4; ot++) {
#pragma unroll
        for (int r = 0; r < 4; r++) {
            int o = ot * 16 + quad * 4 + r;
            out[(b * 64 + o) * HW + opix] = acc[ot][r] + dbv[o];
        }
    }
}

extern "C" void kernel_launch(void* const* d_in, const int* in_sizes, int n_in,
                              void* d_out, int out_size, void* d_ws, size_t ws_size,
                              hipStream_t stream) {
    const float* x   = (const float*)d_in[0];
    const float* ow  = (const float*)d_in[1];
    const float* ob  = (const float*)d_in[2];
    const float* mw  = (const float*)d_in[3];
    const float* mb  = (const float*)d_in[4];
    const float* dw  = (const float*)d_in[5];
    const float* dbv = (const float*)d_in[6];
    float* out = (float*)d_out;

    unsigned short* wpack  = (unsigned short*)d_ws;          // 36864
    unsigned short* wcpack = wpack + 36864;                  // 18432
    unsigned short* xT     = wpack + 55296;                  // 8388608

    prep_transpose<<<2048, 256, 0, stream>>>(x, ow, mw, dw, wpack, wcpack, xT);
    fused_kernel<<<2048, 256, 0, stream>>>(xT, wcpack, wpack, ob, mb, dbv, out);
}

// Round 14
// 145.711 us; speedup vs baseline: 1.5101x; 1.1091x over previous
//
#include <hip/hip_runtime.h>

// Problem constants (B,C,H,W = 8,64,128,128; K=3)
#define BATCH 8
#define CIN   64
#define HW    16384      // 128*128
#define CK    576        // CIN*K2

typedef __attribute__((ext_vector_type(8))) short bf16x8;
typedef __attribute__((ext_vector_type(4))) float f32x4;
typedef __attribute__((ext_vector_type(2))) float f32x2;
typedef __attribute__((ext_vector_type(4))) unsigned u32x4;

__device__ inline unsigned short f2bf(float f) {
    unsigned int u = __builtin_bit_cast(unsigned int, f);
    u += 0x7FFFu + ((u >> 16) & 1u);          // round-to-nearest-even
    return (unsigned short)(u >> 16);
}
__device__ inline float bf2f(unsigned short u) {
    return __builtin_bit_cast(float, (unsigned)u << 16);
}
__device__ inline f32x2 upk2(unsigned u) {    // two bf16 in a dword -> f32x2
    f32x2 r;
    r[0] = __builtin_bit_cast(float, u << 16);
    r[1] = __builtin_bit_cast(float, u & 0xFFFF0000u);
    return r;
}
__device__ inline unsigned pk2bf(f32x2 s) {   // manual RNE pack (cold paths)
    return (unsigned)f2bf(s[0]) | ((unsigned)f2bf(s[1]) << 16);
}
__device__ inline unsigned cvtpk(float lo, float hi) {  // HW RNE pack (hot path)
    unsigned r;
    asm("v_cvt_pk_bf16_f32 %0, %1, %2" : "=v"(r) : "v"(lo), "v"(hi));
    return r;
}

// ---------------- ws layout (ushort units) ----------------
// wpack  [18][4][64][8]  deform A-frags      at 0          (36864)
// wcpack [18][2][64][8]  conv A-frags        at 36864      (18432)
// xT     [B][HW][64]     NHWC bf16 input     at 55296      (8388608)

// Fused prep (blocks 0-143) + NCHW->NHWC bf16 LDS transpose (all 2048 blocks).
__global__ __launch_bounds__(256) void prep_transpose(
        const float* __restrict__ x, const float* __restrict__ ow,
        const float* __restrict__ mw, const float* __restrict__ dw,
        unsigned short* __restrict__ wpack, unsigned short* __restrict__ wcpack,
        unsigned short* __restrict__ xT) {
    __shared__ unsigned tile[64 * 36];   // [px][ch-pair], stride 36 dw (144 B, 16-B aligned)
    int t = threadIdx.x, blk = blockIdx.x;
    int b = blk & 7, r2 = blk >> 3;
    int h = r2 >> 1, hf = r2 & 1;
    int px0 = hf << 6;
    // ---- read phase: coalesced float4 loads, pack channel pairs to bf16 dwords
    {
        const float* __restrict__ xb = x + (b * CIN) * HW + (h << 7) + px0;
#pragma unroll
        for (int r = 0; r < 2; r++) {
            int g = r * 256 + t;            // 512 tasks: 32 ch-pairs x 16 col-chunks
            int c2  = g >> 4;               // channel pair 0..31
            int col = (g & 15) << 2;        // pixel col chunk 0..60
            f32x4 lo = *(const f32x4*)(xb + (2 * c2) * HW + col);
            f32x4 hi = *(const f32x4*)(xb + (2 * c2 + 1) * HW + col);
#pragma unroll
            for (int i = 0; i < 4; i++) {
                f32x2 s; s[0] = lo[i]; s[1] = hi[i];
                tile[(col + i) * 36 + c2] = pk2bf(s);
            }
        }
    }
    __syncthreads();
    // ---- write phase: wave writes 2 KB contiguous (16 px x 128 B records)
    {
        int p = t >> 2, q = t & 3;          // pixel 0..63, 32-B chunk 0..3
        const unsigned* s = &tile[p * 36 + (q << 3)];
        u32x4 v0 = *(const u32x4*)(s);
        u32x4 v1 = *(const u32x4*)(s + 4);
        int pix = (h << 7) + px0 + p;
        unsigned short* dst = xT + ((b * HW + pix) << 6) + (q << 4);
        *(u32x4*)dst = v0;
        *(u32x4*)(dst + 8) = v1;
    }
    // ---- prep part (first 144 blocks)
    int g = blk * 256 + t;
    if (g < 18 * 4 * 64 * 8) {           // deform weights: dw[o][c][tap]
        int j = g & 7, lane = (g >> 3) & 63, ot = (g >> 9) & 3, gks = g >> 11;
        int o = ot * 16 + (lane & 15);
        int s = gks * 32 + ((lane >> 4) & 3) * 8 + j;
        int c = s & 63, tap = s >> 6;
        wpack[g] = f2bf(dw[o * CK + c * 9 + tap]);
    }
    if (g < 18 * 2 * 64 * 8) {           // conv weights: rows 0-17 ow, 18-26 mw
        int j = g & 7, lane = (g >> 3) & 63, ot = (g >> 9) & 1, gks = g >> 10;
        int o = ot * 16 + (lane & 15);
        int s = gks * 32 + ((lane >> 4) & 3) * 8 + j;
        int c = s & 63, tap = s >> 6;
        float v = 0.f;
        if (o < 18)      v = ow[(o * 64 + c) * 9 + tap];
        else if (o < 27) v = mw[((o - 18) * 64 + c) * 9 + tap];
        wcpack[g] = f2bf(v);
    }
}

// Fused offset/mask conv + deformable conv. Block = 64 px (half row).
// R23 = R22's swizzled 25,472-B layout with R20's __launch_bounds__(256,5).
// R22 lesson: the 2nd launch_bounds arg only CAPS the allocator; cap 85 (<
// true live set ~90) caused partial spill (WRITE 32.8->46.3 MB). With cap
// 102 (R20-proven: 48 VGPR, no spill) runtime occupancy = min(LDS: 6 blocks,
// VGPR: 10 waves/SIMD) = 6 blocks/CU — swizzle's LDS saving + relaxed cap.
__global__ __launch_bounds__(256, 5) void fused_kernel(
        const unsigned short* __restrict__ xT, const unsigned short* __restrict__ wcpack,
        const unsigned short* __restrict__ wpack,
        const float* __restrict__ ob, const float* __restrict__ mb,
        const float* __restrict__ dbv, float* __restrict__ out) {
    __shared__ __align__(16) unsigned short buf[12736];   // 25,472 B total
    // tile: 198 rows x 64 ush, XOR-swizzled          [0,12672)  live S1..A
    // lifetime-disjoint overlays:
    unsigned short* omrow = buf;                 // [27][64] ush   [0,1728)    live A-epi..B
    float*          wtab  = (float*)&buf[1728];  // [576][4] f32   [1728,6336) live B..C
    unsigned short* rtab  = &buf[6336];          // [576][4] ush   [6336,8640) live B..C
    unsigned short* stash = &buf[8640];          // 4 waves x 1024 [8640,12736) live C

    int t = threadIdx.x;
    int lane = t & 63, pt = t >> 6, quad = lane >> 4, n = lane & 15;
    int blk = blockIdx.x;
    int b = blk & 7, r2 = blk >> 3;
    int h = r2 >> 1, hf = r2 & 1;
    int px0 = hf << 6;
    int pxl = (pt << 4) + n;          // this lane's pixel within the 64-px block
    int gx  = px0 + pxl;

    const unsigned short* __restrict__ xtb = xT + ((b * HW) << 6);
    const short zs = 0;
    const bf16x8 zv = {zs, zs, zs, zs, zs, zs, zs, zs};

    // ========== Stage 1: halo tile (rows h-1..h+1, cols px0-1..px0+64) ==========
    for (int i = t; i < 1584; i += 256) {       // 198 rows x 8 slices
        int s  = i & 7;
        int rc = i >> 3;                        // 0..197
        int r  = rc / 66, col = rc - r * 66;
        int gy  = h - 1 + r;
        int gxc = px0 - 1 + col;
        bf16x8 v = zv;
        if ((unsigned)gy < 128u && (unsigned)gxc < 128u)
            v = *(const bf16x8*)(xtb + (((gy << 7) + gxc) << 6) + (s << 3));
        *(bf16x8*)&buf[(rc << 6) + (((s ^ (rc & 7)) << 3))] = v;   // swizzled slot
    }
    __syncthreads();

    // ========== Phase A: offset/mask conv from LDS tile (swizzled reads) ==========
    f32x4 acc0 = {0.f, 0.f, 0.f, 0.f}, acc1 = {0.f, 0.f, 0.f, 0.f};
#pragma unroll
    for (int tap = 0; tap < 9; tap++) {
        int r = tap / 3, cm = tap % 3;
        int row = r * 66 + pxl + cm;
        const unsigned short* srcA = &buf[row << 6];
        int rk = (row & 7);
#pragma unroll
        for (int kk = 0; kk < 2; kk++) {
            int slot = (kk << 2) + quad;         // 8-ush slot index 0..7
            bf16x8 bfrag = *(const bf16x8*)(srcA + ((slot ^ rk) << 3));
            int gks = tap * 2 + kk;
            bf16x8 a0 = *(const bf16x8*)(wcpack + ((gks * 2 + 0) * 64 + lane) * 8);
            bf16x8 a1 = *(const bf16x8*)(wcpack + ((gks * 2 + 1) * 64 + lane) * 8);
            acc0 = __builtin_amdgcn_mfma_f32_16x16x32_bf16(a0, bfrag, acc0, 0, 0, 0);
            acc1 = __builtin_amdgcn_mfma_f32_16x16x32_bf16(a1, bfrag, acc1, 0, 0, 0);
        }
    }
    __syncthreads();   // tile reads complete before omrow overwrites tile rows

    // epilogue -> omrow (overlays dead tile rows), o-major [27][64]
#pragma unroll
    for (int r = 0; r < 4; r++) {
        int o = quad * 4 + r;
        omrow[o * 64 + pxl] = f2bf(acc0[r] + ob[o]);
    }
#pragma unroll
    for (int r = 0; r < 4; r++) {
        int o = 16 + quad * 4 + r;
        if (o < 27) {
            float v = acc1[r];
            if (o < 18) v += ob[o];
            else { v += mb[o - 18]; v = 1.f / (1.f + __expf(-v)); }
            omrow[o * 64 + pxl] = f2bf(v);
        }
    }
    __syncthreads();

    // ========== Phase B: full bilinear params -> wtab (f32x4) + rtab (4 rows) ==========
    for (int g = t; g < 576; g += 256) {
        int px = g / 9, k = g - px * 9;
        float dy = bf2f(omrow[(2 * k) * 64 + px]);
        float dx = bf2f(omrow[(2 * k + 1) * 64 + px]);
        float mk = bf2f(omrow[(18 + k) * 64 + px]);
        float py  = (float)h + (float)(k / 3 - 1) + dy;
        float pxx = (float)(px0 + px) + (float)(k % 3 - 1) + dx;
        float fy = floorf(py), fx = floorf(pxx);
        float ly = py - fy, lx = pxx - fx;
        int y0 = (int)fy, x0 = (int)fx;
        bool y0v = (unsigned)y0 < 128u, y1v = (unsigned)(y0 + 1) < 128u;
        bool x0v = (unsigned)x0 < 128u, x1v = (unsigned)(x0 + 1) < 128u;
        f32x4 wv;
        wv[0] = (y0v && x0v) ? (1.f - ly) * (1.f - lx) * mk : 0.f;
        wv[1] = (y0v && x1v) ? (1.f - ly) * lx * mk : 0.f;
        wv[2] = (y1v && x0v) ? ly * (1.f - lx) * mk : 0.f;
        wv[3] = (y1v && x1v) ? ly * lx * mk : 0.f;
        *(f32x4*)&wtab[g * 4] = wv;
        int y0c = min(max(y0, 0), 127), x0c = min(max(x0, 0), 127);
        unsigned dxb = (x0 >= 0 && x0 < 127) ? 1u : 0u;
        unsigned dyb = (y0 >= 0 && y0 < 127) ? 128u : 0u;
        unsigned r00 = (unsigned)((y0c << 7) + x0c);
        uint2 u; u.x = r00 | ((r00 + dxb) << 16); u.y = (r00 + dyb) | ((r00 + dyb + dxb) << 16);
        *(uint2*)&rtab[g * 4] = u;
    }
    __syncthreads();

    // ========== Phase C: combine-before-stash, 1-tap prefetch ==========
    f32x4 acc[4];
#pragma unroll
    for (int ot = 0; ot < 4; ot++) acc[ot] = (f32x4){0.f, 0.f, 0.f, 0.f};

    // gather tasks: lane handles wave-local pixels pxg and pxg+8, slice s7
    int s7    = lane & 7;
    int soffu = s7 << 3;
    int pxg   = lane >> 3;                   // 0..7
    unsigned short* stw = stash + (pt << 10);      // wave's 1024-ush stash
    int swk   = (s7 ^ (pxg & 7)) << 3;             // swizzled slot (same for px, px+8)
    int wadr0 = (pxg << 6) + swk;
    int wadr1 = ((pxg + 8) << 6) + swk;
    int rad0  = (n << 6) + (((quad) ^ (n & 7)) << 3);        // kk=0 slot
    int rad1  = (n << 6) + (((4 + quad) ^ (n & 7)) << 3);    // kk=1 slot
    int ta    = ((pt << 4) + pxg) * 9;       // block-local pixel index
    int tb    = ((pt << 4) + pxg + 8) * 9;

    bf16x8 pf[8];                            // [task 0..1][corner 0..3]
    {
        uint2 ra = *(const uint2*)&rtab[ta * 4];
        uint2 rb = *(const uint2*)&rtab[tb * 4];
        pf[0] = *(const bf16x8*)(xtb + ((ra.x & 0xFFFF) << 6) + soffu);
        pf[1] = *(const bf16x8*)(xtb + ((ra.x >> 16) << 6) + soffu);
        pf[2] = *(const bf16x8*)(xtb + ((ra.y & 0xFFFF) << 6) + soffu);
        pf[3] = *(const bf16x8*)(xtb + ((ra.y >> 16) << 6) + soffu);
        pf[4] = *(const bf16x8*)(xtb + ((rb.x & 0xFFFF) << 6) + soffu);
        pf[5] = *(const bf16x8*)(xtb + ((rb.x >> 16) << 6) + soffu);
        pf[6] = *(const bf16x8*)(xtb + ((rb.y & 0xFFFF) << 6) + soffu);
        pf[7] = *(const bf16x8*)(xtb + ((rb.y >> 16) << 6) + soffu);
    }

#pragma unroll
    for (int tap = 0; tap < 9; tap++) {
        // issue next tap's corner loads (latency hidden behind combine+MFMA)
        bf16x8 nf[8];
        if (tap < 8) {
            uint2 ra = *(const uint2*)&rtab[(ta + tap + 1) * 4];
            uint2 rb = *(const uint2*)&rtab[(tb + tap + 1) * 4];
            nf[0] = *(const bf16x8*)(xtb + ((ra.x & 0xFFFF) << 6) + soffu);
            nf[1] = *(const bf16x8*)(xtb + ((ra.x >> 16) << 6) + soffu);
            nf[2] = *(const bf16x8*)(xtb + ((ra.y & 0xFFFF) << 6) + soffu);
            nf[3] = *(const bf16x8*)(xtb + ((ra.y >> 16) << 6) + soffu);
            nf[4] = *(const bf16x8*)(xtb + ((rb.x & 0xFFFF) << 6) + soffu);
            nf[5] = *(const bf16x8*)(xtb + ((rb.x >> 16) << 6) + soffu);
            nf[6] = *(const bf16x8*)(xtb + ((rb.y & 0xFFFF) << 6) + soffu);
            nf[7] = *(const bf16x8*)(xtb + ((rb.y >> 16) << 6) + soffu);
        }
        // combine both tasks in-register (same math order: w0,w1,w2,w3)
#pragma unroll
        for (int i = 0; i < 2; i++) {
            f32x4 wv = *(const f32x4*)&wtab[((i ? tb : ta) + tap) * 4];
            f32x2 W0 = {wv[0], wv[0]}, W1 = {wv[1], wv[1]};
            f32x2 W2 = {wv[2], wv[2]}, W3 = {wv[3], wv[3]};
            const unsigned* u0 = (const unsigned*)&pf[i * 4 + 0];
            const unsigned* u1 = (const unsigned*)&pf[i * 4 + 1];
            const unsigned* u2 = (const unsigned*)&pf[i * 4 + 2];
            const unsigned* u3 = (const unsigned*)&pf[i * 4 + 3];
            bf16x8 bc;
            unsigned* bu = (unsigned*)&bc;
#pragma unroll
            for (int jj = 0; jj < 4; jj++) {
                f32x2 s2 = upk2(u0[jj]) * W0 + upk2(u1[jj]) * W1
                         + upk2(u2[jj]) * W2 + upk2(u3[jj]) * W3;
                bu[jj] = cvtpk(s2[0], s2[1]);
            }
            *(bf16x8*)&stw[i ? wadr1 : wadr0] = bc;
        }
        // read own pixel's finished bfrags + MFMA (same-wave DS order)
#pragma unroll
        for (int kk = 0; kk < 2; kk++) {
            bf16x8 bfrag = *(const bf16x8*)&stw[kk ? rad1 : rad0];
            int gks = tap * 2 + kk;
#pragma unroll
            for (int ot = 0; ot < 4; ot++) {
                bf16x8 af = *(const bf16x8*)(wpack + ((gks * 4 + ot) * 64 + lane) * 8);
                acc[ot] = __builtin_amdgcn_mfma_f32_16x16x32_bf16(af, bfrag, acc[ot], 0, 0, 0);
            }
        }
        if (tap < 8) {
#pragma unroll
            for (int i = 0; i < 8; i++) pf[i] = nf[i];
        }
    }

    // ---- epilogue: D col(lane&15)=px, row = ot*16 + quad*4 + r = o
    int opix = (h << 7) + px0 + (pt << 4) + n;
#pragma unroll
    for (int ot = 0; ot < 4; ot++) {
#pragma unroll
        for (int r = 0; r < 4; r++) {
            int o = ot * 16 + quad * 4 + r;
            out[(b * 64 + o) * HW + opix] = acc[ot][r] + dbv[o];
        }
    }
}

extern "C" void kernel_launch(void* const* d_in, const int* in_sizes, int n_in,
                              void* d_out, int out_size, void* d_ws, size_t ws_size,
                              hipStream_t stream) {
    const float* x   = (const float*)d_in[0];
    const float* ow  = (const float*)d_in[1];
    const float* ob  = (const float*)d_in[2];
    const float* mw  = (const float*)d_in[3];
    const float* mb  = (const float*)d_in[4];
    const float* dw  = (const float*)d_in[5];
    const float* dbv = (const float*)d_in[6];
    float* out = (float*)d_out;

    unsigned short* wpack  = (unsigned short*)d_ws;          // 36864
    unsigned short* wcpack = wpack + 36864;                  // 18432
    unsigned short* xT     = wpack + 55296;                  // 8388608

    prep_transpose<<<2048, 256, 0, stream>>>(x, ow, mw, dw, wpack, wcpack, xT);
    fused_kernel<<<2048, 256, 0, stream>>>(xT, wcpack, wpack, ob, mb, dbv, out);
}